// Round 1
// baseline (3971.353 us; speedup 1.0000x reference)
//
#include <hip/hip_runtime.h>

#define NN 100000
#define HH 128
#define EE 600000
#define LL 2
#define RR 3
#define AAA 64
#define CC 16

constexpr int XS = 132;  // padded LDS row stride (dwords) -> rows differing by 1 land in different bank-quads

// ---------------- weight fusion ----------------
// grid: LL*RR*HH blocks, 256 threads. block b = lr*128 + i (output row i).
__global__ void k_fuse_w(const float* __restrict__ Wsrc, const float* __restrict__ Wdst,
                         const float* __restrict__ Wupd, float* __restrict__ fWd,
                         float* __restrict__ fWs) {
    int b = blockIdx.x;
    int lr = b >> 7, i = b & 127;
    int t = threadIdx.x;
    int j = t & 127;
    const float* wu = Wupd + (size_t)lr * 2 * HH * HH;
    float acc = 0.f;
    if (t < 128) {
        const float* wd = Wdst + ((size_t)lr * HH + i) * HH;
        for (int k = 0; k < HH; ++k) acc += wd[k] * wu[k * HH + j];
        fWd[((size_t)lr * HH + i) * HH + j] = acc;
    } else {
        const float* wsc = Wsrc + ((size_t)lr * HH + i) * HH;
        for (int k = 0; k < HH; ++k) acc += wsc[k] * wu[(HH + k) * HH + j];
        fWs[((size_t)lr * HH + i) * HH + j] = acc;
    }
}

// grid: LL*RR blocks, 128 threads
__global__ void k_fuse_b(const float* __restrict__ bsrc, const float* __restrict__ bdst,
                         const float* __restrict__ bupd, const float* __restrict__ Wupd,
                         float* __restrict__ fB) {
    int lr = blockIdx.x;
    int j = threadIdx.x;
    const float* wu = Wupd + (size_t)lr * 2 * HH * HH;
    const float* bd = bdst + lr * HH;
    const float* bs = bsrc + lr * HH;
    float acc = bupd[lr * HH + j];
    for (int k = 0; k < HH; ++k)
        acc += bd[k] * wu[k * HH + j] + bs[k] * wu[(HH + k) * HH + j];
    fB[lr * HH + j] = acc;
}

// ---------------- edge aggregation ----------------
__global__ void k_count(const int* __restrict__ dst, float* __restrict__ cnt) {
    int i = blockIdx.x * 256 + threadIdx.x;
    if (i < EE) atomicAdd(&cnt[dst[i]], 1.0f);
}

__global__ void k_inv(float* __restrict__ cnt) {
    int i = blockIdx.x * 256 + threadIdx.x;
    if (i < NN) cnt[i] = 1.0f / fmaxf(cnt[i], 1.0f);
}

// 2 edges per 256-thread block; thread h = tid&127
__global__ __launch_bounds__(256) void k_scatter(float* __restrict__ emb, const float* __restrict__ xs,
                                                 const int* __restrict__ e, const float* __restrict__ ic) {
    int eid = blockIdx.x * 2 + (threadIdx.x >> 7);
    if (eid >= EE) return;
    int h = threadIdx.x & 127;
    int s = e[eid], d = e[EE + eid];
    atomicAdd(&emb[(size_t)d * HH + h], xs[(size_t)s * HH + h] * ic[d]);
}

// ---------------- GEMM: Y (op)= X @ W  (X is [nrows,128], W is [128,128]) ----------------
// MODE 1: Y = X@W   (safe in-place when X==Y: tile staged in LDS first)
// MODE 2: Y += X@W + bias
template <int MODE>
__global__ __launch_bounds__(256) void k_gemm(float* __restrict__ Y, const float* __restrict__ X,
                                              const float* __restrict__ W, const float* __restrict__ bias,
                                              int nrows) {
    __shared__ float Wl[HH * HH];   // 64 KiB
    __shared__ float Xl[HH * XS];   // 66 KiB (padded stride)
    int tid = threadIdx.x;
    int row0 = blockIdx.x * 128;
    for (int i = tid * 4; i < HH * HH; i += 1024)
        *(float4*)&Wl[i] = *(const float4*)&W[i];
    for (int idx = tid; idx < 128 * 32; idx += 256) {
        int r = idx >> 5, cw = idx & 31;
        float4 v = make_float4(0.f, 0.f, 0.f, 0.f);
        if (row0 + r < nrows) v = *(const float4*)&X[(size_t)(row0 + r) * HH + cw * 4];
        *(float4*)&Xl[r * XS + cw * 4] = v;
    }
    __syncthreads();
    int tx = tid & 15, ty = tid >> 4;
    // thread tile: rows ty+16*i (i<8), cols {tx*4..+3} and {64+tx*4..+3}
    float acc[8][8];
#pragma unroll
    for (int i = 0; i < 8; ++i)
#pragma unroll
        for (int j = 0; j < 8; ++j) acc[i][j] = 0.f;

#pragma unroll 4
    for (int k = 0; k < HH; k += 4) {
        float4 xv[8];
#pragma unroll
        for (int i = 0; i < 8; ++i) xv[i] = *(const float4*)&Xl[(ty + 16 * i) * XS + k];
#pragma unroll
        for (int kk = 0; kk < 4; ++kk) {
            float4 w0 = *(const float4*)&Wl[(k + kk) * HH + tx * 4];
            float4 w1 = *(const float4*)&Wl[(k + kk) * HH + 64 + tx * 4];
#pragma unroll
            for (int i = 0; i < 8; ++i) {
                float xsv = (&xv[i].x)[kk];
                acc[i][0] += xsv * w0.x; acc[i][1] += xsv * w0.y;
                acc[i][2] += xsv * w0.z; acc[i][3] += xsv * w0.w;
                acc[i][4] += xsv * w1.x; acc[i][5] += xsv * w1.y;
                acc[i][6] += xsv * w1.z; acc[i][7] += xsv * w1.w;
            }
        }
    }
    float4 b0 = make_float4(0.f, 0.f, 0.f, 0.f), b1 = b0;
    if (MODE == 2) {
        b0 = *(const float4*)&bias[tx * 4];
        b1 = *(const float4*)&bias[64 + tx * 4];
    }
#pragma unroll
    for (int i = 0; i < 8; ++i) {
        int r = row0 + ty + 16 * i;
        if (r >= nrows) continue;
        float* yp = Y + (size_t)r * HH + tx * 4;
        if (MODE == 1) {
            *(float4*)yp = make_float4(acc[i][0], acc[i][1], acc[i][2], acc[i][3]);
            *(float4*)(yp + 64) = make_float4(acc[i][4], acc[i][5], acc[i][6], acc[i][7]);
        } else {
            float4 o0 = *(float4*)yp, o1 = *(float4*)(yp + 64);
            o0.x += acc[i][0] + b0.x; o0.y += acc[i][1] + b0.y;
            o0.z += acc[i][2] + b0.z; o0.w += acc[i][3] + b0.w;
            o1.x += acc[i][4] + b1.x; o1.y += acc[i][5] + b1.y;
            o1.z += acc[i][6] + b1.z; o1.w += acc[i][7] + b1.w;
            *(float4*)yp = o0; *(float4*)(yp + 64) = o1;
        }
    }
}

// ---------------- attention score: partial[b] = sum over block's nodes of tanh(x@W1+b1)@w2 ----------------
__global__ __launch_bounds__(256) void k_attn(const float* __restrict__ X, const float* __restrict__ W1,
                                              const float* __restrict__ b1, const float* __restrict__ w2,
                                              float* __restrict__ partial, int nrows) {
    __shared__ float W1l[HH * AAA];  // 32 KiB
    __shared__ float red[4];
    int tid = threadIdx.x;
    for (int i = tid * 4; i < HH * AAA; i += 1024)
        *(float4*)&W1l[i] = *(const float4*)&W1[i];
    int lane = tid & 63, wv = tid >> 6;
    float b1v = b1[lane], w2v = w2[lane];
    __syncthreads();
    float acc = 0.f;
    for (int n = blockIdx.x * 4 + wv; n < nrows; n += gridDim.x * 4) {
        const float4* x4 = (const float4*)(X + (size_t)n * HH);
        float s = b1v;
#pragma unroll
        for (int h4 = 0; h4 < 32; ++h4) {
            float4 xv = x4[h4];
            s += xv.x * W1l[(h4 * 4 + 0) * AAA + lane];
            s += xv.y * W1l[(h4 * 4 + 1) * AAA + lane];
            s += xv.z * W1l[(h4 * 4 + 2) * AAA + lane];
            s += xv.w * W1l[(h4 * 4 + 3) * AAA + lane];
        }
        acc += tanhf(s) * w2v;
    }
#pragma unroll
    for (int off = 32; off > 0; off >>= 1) acc += __shfl_down(acc, off);
    if (lane == 0) red[wv] = acc;
    __syncthreads();
    if (tid == 0) partial[blockIdx.x] = red[0] + red[1] + red[2] + red[3];
}

__global__ void k_alpha(const float* __restrict__ P1, const float* __restrict__ P2,
                        float* __restrict__ alpha, int nparts, float invn) {
    __shared__ float s1[256], s2[256];
    int tid = threadIdx.x;
    float a = 0.f, b = 0.f;
    for (int i = tid; i < nparts; i += 256) { a += P1[i]; b += P2[i]; }
    s1[tid] = a; s2[tid] = b;
    __syncthreads();
    for (int off = 128; off > 0; off >>= 1) {
        if (tid < off) { s1[tid] += s1[tid + off]; s2[tid] += s2[tid + off]; }
        __syncthreads();
    }
    if (tid == 0) {
        float m1 = s1[0] * invn, m2 = s2[0] * invn;
        float mx = fmaxf(m1, m2);
        float e1 = expf(m1 - mx), e2 = expf(m2 - mx);
        float inv = 1.f / (e1 + e2);
        alpha[0] = e1 * inv; alpha[1] = e2 * inv;
    }
}

// ---------------- combine (optional) + column stats ----------------
template <bool COMBINE>
__global__ __launch_bounds__(256) void k_comb(float* __restrict__ X, const float* __restrict__ Y,
                                              const float* __restrict__ alpha, float* __restrict__ colsum,
                                              float* __restrict__ colsq, int nrows) {
    int tid = threadIdx.x;
    int h = tid & 127, half = tid >> 7;
    float a0 = 1.f, a1 = 0.f;
    if (COMBINE) { a0 = alpha[0]; a1 = alpha[1]; }
    float s = 0.f, q = 0.f;
    for (int n = blockIdx.x * 2 + half; n < nrows; n += gridDim.x * 2) {
        size_t off = (size_t)n * HH + h;
        float v = X[off];
        if (COMBINE) { v = a0 * v + a1 * Y[off]; X[off] = v; }
        s += v; q += v * v;
    }
    __shared__ float ls[256], lq[256];
    ls[tid] = s; lq[tid] = q;
    __syncthreads();
    if (half == 0) {
        atomicAdd(&colsum[h], ls[tid] + ls[tid + 128]);
        atomicAdd(&colsq[h], lq[tid] + lq[tid + 128]);
    }
}

__global__ void k_bnp(const float* __restrict__ sum, const float* __restrict__ sq,
                      const float* __restrict__ gamma, const float* __restrict__ beta,
                      float* __restrict__ scale, float* __restrict__ shift, float invn) {
    int h = threadIdx.x;
    float mu = sum[h] * invn;
    float var = sq[h] * invn - mu * mu;
    float sc = gamma[h] * rsqrtf(var + 1.0f);   // BN_EPS = 1.0
    scale[h] = sc;
    shift[h] = beta[h] - mu * sc;
}

// BN apply + leaky; grid exact N*H/4/256
__global__ void k_bna(float* __restrict__ X, const float* __restrict__ scale,
                      const float* __restrict__ shift) {
    int i = blockIdx.x * 256 + threadIdx.x;
    float4 v = ((float4*)X)[i];
    int h0 = (i & 31) * 4;
    float4 sc = *(const float4*)&scale[h0];
    float4 sf = *(const float4*)&shift[h0];
    v.x = v.x * sc.x + sf.x; v.y = v.y * sc.y + sf.y;
    v.z = v.z * sc.z + sf.z; v.w = v.w * sc.w + sf.w;
    v.x = v.x >= 0.f ? v.x : 0.01f * v.x;
    v.y = v.y >= 0.f ? v.y : 0.01f * v.y;
    v.z = v.z >= 0.f ? v.z : 0.01f * v.z;
    v.w = v.w >= 0.f ? v.w : 0.01f * v.w;
    ((float4*)X)[i] = v;
}

// ---------------- final FC [N,128]@[128,16]+b ----------------
__global__ __launch_bounds__(256) void k_fc(const float* __restrict__ X, const float* __restrict__ W,
                                            const float* __restrict__ b, float* __restrict__ out, int nrows) {
    __shared__ float Wl[HH * CC];
    __shared__ float bl[CC];
    int tid = threadIdx.x;
    for (int i = tid * 4; i < HH * CC; i += 1024)
        *(float4*)&Wl[i] = *(const float4*)&W[i];
    if (tid < CC) bl[tid] = b[tid];
    __syncthreads();
    int c = tid & 15, nl = tid >> 4;
    for (int n = blockIdx.x * 16 + nl; n < nrows; n += gridDim.x * 16) {
        const float4* x4 = (const float4*)(X + (size_t)n * HH);
        float acc = bl[c];
#pragma unroll
        for (int h4 = 0; h4 < 32; ++h4) {
            float4 xv = x4[h4];
            acc += xv.x * Wl[(h4 * 4 + 0) * CC + c] + xv.y * Wl[(h4 * 4 + 1) * CC + c] +
                   xv.z * Wl[(h4 * 4 + 2) * CC + c] + xv.w * Wl[(h4 * 4 + 3) * CC + c];
        }
        out[(size_t)n * CC + c] = acc;
    }
}

extern "C" void kernel_launch(void* const* d_in, const int* in_sizes, int n_in,
                              void* d_out, int out_size, void* d_ws, size_t ws_size,
                              hipStream_t stream) {
    const float* xA = (const float*)d_in[0];
    const float* xB = (const float*)d_in[1];
    const float* Wsrc = (const float*)d_in[2];
    const float* bsrc = (const float*)d_in[3];
    const float* Wdst = (const float*)d_in[4];
    const float* bdst = (const float*)d_in[5];
    const float* Wupd = (const float*)d_in[6];
    const float* bupd = (const float*)d_in[7];
    const float* attnW1 = (const float*)d_in[8];
    const float* attnb1 = (const float*)d_in[9];
    const float* attnw2 = (const float*)d_in[10];
    const float* gamma = (const float*)d_in[11];
    const float* beta = (const float*)d_in[12];
    const float* fcW = (const float*)d_in[13];
    const float* fcb = (const float*)d_in[14];
    const int* eAB = (const int*)d_in[15];
    const int* eBB = (const int*)d_in[16];
    const int* eBA = (const int*)d_in[17];
    float* out = (float*)d_out;

    // workspace layout (~197 MiB total)
    float* ws = (float*)d_ws;
    const size_t NH = (size_t)NN * HH;
    float* B0 = ws;
    float* B1 = B0 + NH;
    float* B2 = B1 + NH;
    float* B3 = B2 + NH;
    float* fWd = B3 + NH;                       // L*R*H*H
    float* fWs = fWd + (size_t)LL * RR * HH * HH;
    float* fB = fWs + (size_t)LL * RR * HH * HH; // L*R*H
    float* cnt = fB + LL * RR * HH;              // N
    float* csA = cnt + NN;                       // colsumA[128] colsqA[128]
    float* csB = csA + 256;
    float* scA = csB + 256;                      // scaleA[128] shiftA[128]
    float* scB = scA + 256;
    float* P1 = scB + 256;                       // 1024
    float* P2 = P1 + 1024;
    float* alp = P2 + 1024;                      // 2
    const float invN = 1.0f / (float)NN;

    k_fuse_w<<<LL * RR * HH, 256, 0, stream>>>(Wsrc, Wdst, Wupd, fWd, fWs);
    k_fuse_b<<<LL * RR, HH, 0, stream>>>(bsrc, bdst, bupd, Wupd, fB);

    const int GEMM_GRID = (NN + 127) / 128;

    auto conv = [&](float* emb, const float* xs, const float* xd, const int* e, int lr) {
        hipMemsetAsync(emb, 0, NH * 4, stream);
        hipMemsetAsync(cnt, 0, NN * 4, stream);
        k_count<<<(EE + 255) / 256, 256, 0, stream>>>(e + EE, cnt);
        k_inv<<<(NN + 255) / 256, 256, 0, stream>>>(cnt);
        k_scatter<<<EE / 2, 256, 0, stream>>>(emb, xs, e, cnt);
        k_gemm<1><<<GEMM_GRID, 256, 0, stream>>>(emb, emb, fWs + (size_t)lr * HH * HH, nullptr, NN);
        k_gemm<2><<<GEMM_GRID, 256, 0, stream>>>(emb, xd, fWd + (size_t)lr * HH * HH, fB + lr * HH, NN);
    };

    // ================= layer 0 =================
    conv(B0, xA, xB, eAB, 0);  // embB1
    conv(B1, xB, xB, eBB, 1);  // embB2
    conv(B2, xB, xA, eBA, 2);  // embA
    k_attn<<<1024, 256, 0, stream>>>(B0, attnW1, attnb1, attnw2, P1, NN);
    k_attn<<<1024, 256, 0, stream>>>(B1, attnW1, attnb1, attnw2, P2, NN);
    k_alpha<<<1, 256, 0, stream>>>(P1, P2, alp, 1024, invN);
    hipMemsetAsync(csB, 0, 256 * 4, stream);
    k_comb<true><<<512, 256, 0, stream>>>(B0, B1, alp, csB, csB + 128, NN);  // xB_new -> B0
    hipMemsetAsync(csA, 0, 256 * 4, stream);
    k_comb<false><<<512, 256, 0, stream>>>(B2, nullptr, nullptr, csA, csA + 128, NN);
    k_bnp<<<1, 128, 0, stream>>>(csA, csA + 128, gamma + 0 * HH, beta + 0 * HH, scA, scA + 128, invN);
    k_bnp<<<1, 128, 0, stream>>>(csB, csB + 128, gamma + 1 * HH, beta + 1 * HH, scB, scB + 128, invN);
    k_bna<<<(int)(NH / 4 / 256), 256, 0, stream>>>(B2, scA, scA + 128);  // xA = B2
    k_bna<<<(int)(NH / 4 / 256), 256, 0, stream>>>(B0, scB, scB + 128);  // xB = B0

    // ================= layer 1 =================
    conv(B1, B2, B0, eAB, 3);  // embB1'
    conv(B3, B0, B0, eBB, 4);  // embB2'
    k_attn<<<1024, 256, 0, stream>>>(B1, attnW1 + HH * AAA, attnb1 + AAA, attnw2 + AAA, P1, NN);
    k_attn<<<1024, 256, 0, stream>>>(B3, attnW1 + HH * AAA, attnb1 + AAA, attnw2 + AAA, P2, NN);
    k_alpha<<<1, 256, 0, stream>>>(P1, P2, alp, 1024, invN);
    hipMemsetAsync(csB, 0, 256 * 4, stream);
    k_comb<true><<<512, 256, 0, stream>>>(B1, B3, alp, csB, csB + 128, NN);  // xB_new -> B1, frees B3
    conv(B3, B0, B2, eBA, 5);  // embA' (reads B0, B2; writes B3)
    hipMemsetAsync(csA, 0, 256 * 4, stream);
    k_comb<false><<<512, 256, 0, stream>>>(B3, nullptr, nullptr, csA, csA + 128, NN);
    k_bnp<<<1, 128, 0, stream>>>(csA, csA + 128, gamma + 2 * HH, beta + 2 * HH, scA, scA + 128, invN);
    k_bnp<<<1, 128, 0, stream>>>(csB, csB + 128, gamma + 3 * HH, beta + 3 * HH, scB, scB + 128, invN);
    k_bna<<<(int)(NH / 4 / 256), 256, 0, stream>>>(B3, scA, scA + 128);  // xA_final = B3
    k_bna<<<(int)(NH / 4 / 256), 256, 0, stream>>>(B1, scB, scB + 128);  // xB_final = B1

    // ================= head =================
    k_fc<<<2048, 256, 0, stream>>>(B3, fcW, fcb, out, NN);
    k_fc<<<2048, 256, 0, stream>>>(B1, fcW + HH * CC, fcb + CC, out + (size_t)NN * CC, NN);
}

// Round 2
// 2510.498 us; speedup vs baseline: 1.5819x; 1.5819x over previous
//
#include <hip/hip_runtime.h>

#define NN 100000
#define HH 128
#define EE 600000
#define LL 2
#define RR 3
#define AAA 64
#define CC 16
#define SCAN_B 98   // 98 blocks x 1024 elems covers 100000

constexpr int XS = 132;  // padded LDS row stride (dwords)

// ---------------- weight fusion ----------------
__global__ void k_fuse_w(const float* __restrict__ Wsrc, const float* __restrict__ Wdst,
                         const float* __restrict__ Wupd, float* __restrict__ fWd,
                         float* __restrict__ fWs) {
    int b = blockIdx.x;
    int lr = b >> 7, i = b & 127;
    int t = threadIdx.x;
    int j = t & 127;
    const float* wu = Wupd + (size_t)lr * 2 * HH * HH;
    float acc = 0.f;
    if (t < 128) {
        const float* wd = Wdst + ((size_t)lr * HH + i) * HH;
        for (int k = 0; k < HH; ++k) acc += wd[k] * wu[k * HH + j];
        fWd[((size_t)lr * HH + i) * HH + j] = acc;
    } else {
        const float* wsc = Wsrc + ((size_t)lr * HH + i) * HH;
        for (int k = 0; k < HH; ++k) acc += wsc[k] * wu[(HH + k) * HH + j];
        fWs[((size_t)lr * HH + i) * HH + j] = acc;
    }
}

__global__ void k_fuse_b(const float* __restrict__ bsrc, const float* __restrict__ bdst,
                         const float* __restrict__ bupd, const float* __restrict__ Wupd,
                         float* __restrict__ fB) {
    int lr = blockIdx.x;
    int j = threadIdx.x;
    const float* wu = Wupd + (size_t)lr * 2 * HH * HH;
    const float* bd = bdst + lr * HH;
    const float* bs = bsrc + lr * HH;
    float acc = bupd[lr * HH + j];
    for (int k = 0; k < HH; ++k)
        acc += bd[k] * wu[k * HH + j] + bs[k] * wu[(HH + k) * HH + j];
    fB[lr * HH + j] = acc;
}

// ---------------- CSR build ----------------
__global__ void k_count(const int* __restrict__ dst, int* __restrict__ cnt) {
    int i = blockIdx.x * 256 + threadIdx.x;
    if (i < EE) atomicAdd(&cnt[dst[i]], 1);
}

// exclusive scan over cnt[NN] -> rs[NN]; per-block (1024 elems) with block sums
__global__ void k_scan1(const int* __restrict__ cnt, int* __restrict__ rs, int* __restrict__ bsum) {
    __shared__ int sd[256];
    int blk = blockIdx.x, tid = threadIdx.x;
    int base = blk * 1024 + tid * 4;
    int c0 = 0, c1 = 0, c2 = 0, c3 = 0;
    if (base + 0 < NN) c0 = cnt[base + 0];
    if (base + 1 < NN) c1 = cnt[base + 1];
    if (base + 2 < NN) c2 = cnt[base + 2];
    if (base + 3 < NN) c3 = cnt[base + 3];
    int s = c0 + c1 + c2 + c3;
    sd[tid] = s;
    __syncthreads();
    for (int off = 1; off < 256; off <<= 1) {
        int v = (tid >= off) ? sd[tid - off] : 0;
        __syncthreads();
        sd[tid] += v;
        __syncthreads();
    }
    int excl = sd[tid] - s;
    if (tid == 255) bsum[blk] = sd[255];
    if (base + 0 < NN) rs[base + 0] = excl;
    if (base + 1 < NN) rs[base + 1] = excl + c0;
    if (base + 2 < NN) rs[base + 2] = excl + c0 + c1;
    if (base + 3 < NN) rs[base + 3] = excl + c0 + c1 + c2;
}

__global__ void k_scan2(int* __restrict__ bsum) {  // 1 block, 128 threads
    __shared__ int sd[128];
    int tid = threadIdx.x;
    int v = (tid < SCAN_B) ? bsum[tid] : 0;
    sd[tid] = v;
    __syncthreads();
    for (int off = 1; off < 128; off <<= 1) {
        int u = (tid >= off) ? sd[tid - off] : 0;
        __syncthreads();
        sd[tid] += u;
        __syncthreads();
    }
    if (tid < SCAN_B) bsum[tid] = sd[tid] - v;  // exclusive
}

__global__ void k_scan3(int* __restrict__ rs, const int* __restrict__ bsum) {
    int i = blockIdx.x * 256 + threadIdx.x;
    if (i < NN) rs[i] += bsum[i >> 10];
}

__global__ void k_fill(const int* __restrict__ e, int* __restrict__ fill,
                       const int* __restrict__ rs, int* __restrict__ csr) {
    int i = blockIdx.x * 256 + threadIdx.x;
    if (i >= EE) return;
    int s = e[i], d = e[EE + i];
    int pos = rs[d] + atomicAdd(&fill[d], 1);
    csr[pos] = s;
}

// ---------------- aggregation: one wave per dst node ----------------
__global__ __launch_bounds__(256) void k_aggr(float* __restrict__ emb, const float* __restrict__ xs,
                                              const int* __restrict__ rs, const int* __restrict__ cnt,
                                              const int* __restrict__ csr) {
    int node = blockIdx.x * 4 + (threadIdx.x >> 6);
    if (node >= NN) return;
    int lane = threadIdx.x & 63;
    int beg = rs[node], deg = cnt[node];
    const float2* xs2 = (const float2*)xs;
    float ax = 0.f, ay = 0.f;
    int j = 0;
    for (; j + 1 < deg; j += 2) {
        int s0 = csr[beg + j], s1 = csr[beg + j + 1];
        float2 v0 = xs2[(size_t)s0 * 64 + lane];
        float2 v1 = xs2[(size_t)s1 * 64 + lane];
        ax += v0.x + v1.x;
        ay += v0.y + v1.y;
    }
    if (j < deg) {
        float2 v = xs2[(size_t)csr[beg + j] * 64 + lane];
        ax += v.x;
        ay += v.y;
    }
    float sc = 1.0f / fmaxf((float)deg, 1.0f);
    ((float2*)emb)[(size_t)node * 64 + lane] = make_float2(ax * sc, ay * sc);
}

// ---------------- fused conv GEMM: Y = X1@W1 + X2@W2 + bias (in-place safe for X1==Y) ----------------
__global__ __launch_bounds__(256) void k_cgemm(float* __restrict__ Y, const float* __restrict__ X1,
                                               const float* __restrict__ X2, const float* __restrict__ W1f,
                                               const float* __restrict__ W2f, const float* __restrict__ bias,
                                               int nrows) {
    __shared__ float Wl[HH * HH];   // 64 KiB
    __shared__ float Xl[128 * XS];  // 66 KiB
    int tid = threadIdx.x;
    int row0 = blockIdx.x * 128;
    int tx = tid & 15, ty = tid >> 4;
    float acc[8][8];
#pragma unroll
    for (int i = 0; i < 8; ++i)
#pragma unroll
        for (int j = 0; j < 8; ++j) acc[i][j] = 0.f;

    for (int ph = 0; ph < 2; ++ph) {
        if (ph) __syncthreads();  // all compute on old tiles done before restage
        const float* W = ph ? W2f : W1f;
        const float* X = ph ? X2 : X1;
        for (int i = tid * 4; i < HH * HH; i += 1024)
            *(float4*)&Wl[i] = *(const float4*)&W[i];
        for (int idx = tid; idx < 128 * 32; idx += 256) {
            int r = idx >> 5, cw = idx & 31;
            float4 v = make_float4(0.f, 0.f, 0.f, 0.f);
            if (row0 + r < nrows) v = *(const float4*)&X[(size_t)(row0 + r) * HH + cw * 4];
            *(float4*)&Xl[r * XS + cw * 4] = v;
        }
        __syncthreads();
#pragma unroll 4
        for (int k = 0; k < HH; k += 4) {
            float4 xv[8];
#pragma unroll
            for (int i = 0; i < 8; ++i) xv[i] = *(const float4*)&Xl[(ty + 16 * i) * XS + k];
#pragma unroll
            for (int kk = 0; kk < 4; ++kk) {
                float4 w0 = *(const float4*)&Wl[(k + kk) * HH + tx * 4];
                float4 w1 = *(const float4*)&Wl[(k + kk) * HH + 64 + tx * 4];
#pragma unroll
                for (int i = 0; i < 8; ++i) {
                    float xsv = (&xv[i].x)[kk];
                    acc[i][0] += xsv * w0.x; acc[i][1] += xsv * w0.y;
                    acc[i][2] += xsv * w0.z; acc[i][3] += xsv * w0.w;
                    acc[i][4] += xsv * w1.x; acc[i][5] += xsv * w1.y;
                    acc[i][6] += xsv * w1.z; acc[i][7] += xsv * w1.w;
                }
            }
        }
    }
    float4 b0 = *(const float4*)&bias[tx * 4];
    float4 b1 = *(const float4*)&bias[64 + tx * 4];
#pragma unroll
    for (int i = 0; i < 8; ++i) {
        int r = row0 + ty + 16 * i;
        if (r >= nrows) continue;
        float* yp = Y + (size_t)r * HH + tx * 4;
        *(float4*)yp = make_float4(acc[i][0] + b0.x, acc[i][1] + b0.y, acc[i][2] + b0.z, acc[i][3] + b0.w);
        *(float4*)(yp + 64) = make_float4(acc[i][4] + b1.x, acc[i][5] + b1.y, acc[i][6] + b1.z, acc[i][7] + b1.w);
    }
}

// ---------------- attention score partials ----------------
__global__ __launch_bounds__(256) void k_attn(const float* __restrict__ X, const float* __restrict__ W1,
                                              const float* __restrict__ b1, const float* __restrict__ w2,
                                              float* __restrict__ partial, int nrows) {
    __shared__ float W1l[HH * AAA];
    __shared__ float red[4];
    int tid = threadIdx.x;
    for (int i = tid * 4; i < HH * AAA; i += 1024)
        *(float4*)&W1l[i] = *(const float4*)&W1[i];
    int lane = tid & 63, wv = tid >> 6;
    float b1v = b1[lane], w2v = w2[lane];
    __syncthreads();
    float acc = 0.f;
    for (int n = blockIdx.x * 4 + wv; n < nrows; n += gridDim.x * 4) {
        const float4* x4 = (const float4*)(X + (size_t)n * HH);
        float s = b1v;
#pragma unroll
        for (int h4 = 0; h4 < 32; ++h4) {
            float4 xv = x4[h4];
            s += xv.x * W1l[(h4 * 4 + 0) * AAA + lane];
            s += xv.y * W1l[(h4 * 4 + 1) * AAA + lane];
            s += xv.z * W1l[(h4 * 4 + 2) * AAA + lane];
            s += xv.w * W1l[(h4 * 4 + 3) * AAA + lane];
        }
        acc += tanhf(s) * w2v;
    }
#pragma unroll
    for (int off = 32; off > 0; off >>= 1) acc += __shfl_down(acc, off);
    if (lane == 0) red[wv] = acc;
    __syncthreads();
    if (tid == 0) partial[blockIdx.x] = red[0] + red[1] + red[2] + red[3];
}

__global__ void k_alpha(const float* __restrict__ P1, const float* __restrict__ P2,
                        float* __restrict__ alpha, int nparts, float invn) {
    __shared__ float s1[256], s2[256];
    int tid = threadIdx.x;
    float a = 0.f, b = 0.f;
    for (int i = tid; i < nparts; i += 256) { a += P1[i]; b += P2[i]; }
    s1[tid] = a; s2[tid] = b;
    __syncthreads();
    for (int off = 128; off > 0; off >>= 1) {
        if (tid < off) { s1[tid] += s1[tid + off]; s2[tid] += s2[tid + off]; }
        __syncthreads();
    }
    if (tid == 0) {
        float m1 = s1[0] * invn, m2 = s2[0] * invn;
        float mx = fmaxf(m1, m2);
        float e1 = expf(m1 - mx), e2 = expf(m2 - mx);
        float inv = 1.f / (e1 + e2);
        alpha[0] = e1 * inv; alpha[1] = e2 * inv;
    }
}

// ---------------- combine + column stats ----------------
template <bool COMBINE>
__global__ __launch_bounds__(256) void k_comb(float* __restrict__ X, const float* __restrict__ Y,
                                              const float* __restrict__ alpha, float* __restrict__ colsum,
                                              float* __restrict__ colsq, int nrows) {
    int tid = threadIdx.x;
    int h = tid & 127, half = tid >> 7;
    float a0 = 1.f, a1 = 0.f;
    if (COMBINE) { a0 = alpha[0]; a1 = alpha[1]; }
    float s = 0.f, q = 0.f;
    for (int n = blockIdx.x * 2 + half; n < nrows; n += gridDim.x * 2) {
        size_t off = (size_t)n * HH + h;
        float v = X[off];
        if (COMBINE) { v = a0 * v + a1 * Y[off]; X[off] = v; }
        s += v; q += v * v;
    }
    __shared__ float ls[256], lq[256];
    ls[tid] = s; lq[tid] = q;
    __syncthreads();
    if (half == 0) {
        atomicAdd(&colsum[h], ls[tid] + ls[tid + 128]);
        atomicAdd(&colsq[h], lq[tid] + lq[tid + 128]);
    }
}

__global__ void k_bnp(const float* __restrict__ sum, const float* __restrict__ sq,
                      const float* __restrict__ gamma, const float* __restrict__ beta,
                      float* __restrict__ scale, float* __restrict__ shift, float invn) {
    int h = threadIdx.x;
    float mu = sum[h] * invn;
    float var = sq[h] * invn - mu * mu;
    float sc = gamma[h] * rsqrtf(var + 1.0f);
    scale[h] = sc;
    shift[h] = beta[h] - mu * sc;
}

__global__ void k_bna(float* __restrict__ X, const float* __restrict__ scale,
                      const float* __restrict__ shift) {
    int i = blockIdx.x * 256 + threadIdx.x;
    float4 v = ((float4*)X)[i];
    int h0 = (i & 31) * 4;
    float4 sc = *(const float4*)&scale[h0];
    float4 sf = *(const float4*)&shift[h0];
    v.x = v.x * sc.x + sf.x; v.y = v.y * sc.y + sf.y;
    v.z = v.z * sc.z + sf.z; v.w = v.w * sc.w + sf.w;
    v.x = v.x >= 0.f ? v.x : 0.01f * v.x;
    v.y = v.y >= 0.f ? v.y : 0.01f * v.y;
    v.z = v.z >= 0.f ? v.z : 0.01f * v.z;
    v.w = v.w >= 0.f ? v.w : 0.01f * v.w;
    ((float4*)X)[i] = v;
}

// ---------------- final FC ----------------
__global__ __launch_bounds__(256) void k_fc(const float* __restrict__ X, const float* __restrict__ W,
                                            const float* __restrict__ b, float* __restrict__ out, int nrows) {
    __shared__ float Wl[HH * CC];
    __shared__ float bl[CC];
    int tid = threadIdx.x;
    for (int i = tid * 4; i < HH * CC; i += 1024)
        *(float4*)&Wl[i] = *(const float4*)&W[i];
    if (tid < CC) bl[tid] = b[tid];
    __syncthreads();
    int c = tid & 15, nl = tid >> 4;
    for (int n = blockIdx.x * 16 + nl; n < nrows; n += gridDim.x * 16) {
        const float4* x4 = (const float4*)(X + (size_t)n * HH);
        float acc = bl[c];
#pragma unroll
        for (int h4 = 0; h4 < 32; ++h4) {
            float4 xv = x4[h4];
            acc += xv.x * Wl[(h4 * 4 + 0) * CC + c] + xv.y * Wl[(h4 * 4 + 1) * CC + c] +
                   xv.z * Wl[(h4 * 4 + 2) * CC + c] + xv.w * Wl[(h4 * 4 + 3) * CC + c];
        }
        out[(size_t)n * CC + c] = acc;
    }
}

extern "C" void kernel_launch(void* const* d_in, const int* in_sizes, int n_in,
                              void* d_out, int out_size, void* d_ws, size_t ws_size,
                              hipStream_t stream) {
    const float* Wsrc = (const float*)d_in[2];
    const float* bsrc = (const float*)d_in[3];
    const float* Wdst = (const float*)d_in[4];
    const float* bdst = (const float*)d_in[5];
    const float* Wupd = (const float*)d_in[6];
    const float* bupd = (const float*)d_in[7];
    const float* attnW1 = (const float*)d_in[8];
    const float* attnb1 = (const float*)d_in[9];
    const float* attnw2 = (const float*)d_in[10];
    const float* gamma = (const float*)d_in[11];
    const float* beta = (const float*)d_in[12];
    const float* fcW = (const float*)d_in[13];
    const float* fcb = (const float*)d_in[14];
    const float* xA = (const float*)d_in[0];
    const float* xB = (const float*)d_in[1];
    const int* eAB = (const int*)d_in[15];
    const int* eBB = (const int*)d_in[16];
    const int* eBA = (const int*)d_in[17];
    float* out = (float*)d_out;

    float* ws = (float*)d_ws;
    const size_t NH = (size_t)NN * HH;
    float* B0 = ws;
    float* B1 = B0 + NH;
    float* B2 = B1 + NH;
    float* B3 = B2 + NH;
    float* fWd = B3 + NH;
    float* fWs = fWd + (size_t)LL * RR * HH * HH;
    float* fB = fWs + (size_t)LL * RR * HH * HH;
    float* csA = fB + LL * RR * HH;
    float* csB = csA + 256;
    float* scA = csB + 256;
    float* scB = scA + 256;
    float* P1 = scB + 256;
    float* P2 = P1 + 1024;
    float* alp = P2 + 1024;
    // int region: 3x CSR + scratch
    int* icnt = (int*)(alp + 64);
    int* irs = icnt + 3 * NN;
    int* icsr = irs + 3 * NN;
    int* ifill = icsr + 3 * EE;
    int* ibsum = ifill + NN;
    const float invN = 1.0f / (float)NN;

    k_fuse_w<<<LL * RR * HH, 256, 0, stream>>>(Wsrc, Wdst, Wupd, fWd, fWs);
    k_fuse_b<<<LL * RR, HH, 0, stream>>>(bsrc, bdst, bupd, Wupd, fB);

    const int* eArr[3] = {eAB, eBB, eBA};
    for (int r = 0; r < 3; ++r) {
        const int* e = eArr[r];
        int* cnt = icnt + r * NN;
        int* rs = irs + r * NN;
        int* csr = icsr + (size_t)r * EE;
        hipMemsetAsync(cnt, 0, NN * 4, stream);
        hipMemsetAsync(ifill, 0, NN * 4, stream);
        k_count<<<(EE + 255) / 256, 256, 0, stream>>>(e + EE, cnt);
        k_scan1<<<SCAN_B, 256, 0, stream>>>(cnt, rs, ibsum);
        k_scan2<<<1, 128, 0, stream>>>(ibsum);
        k_scan3<<<(NN + 255) / 256, 256, 0, stream>>>(rs, ibsum);
        k_fill<<<(EE + 255) / 256, 256, 0, stream>>>(e, ifill, rs, csr);
    }

    const int GEMM_GRID = (NN + 127) / 128;
    const int AGGR_GRID = (NN + 3) / 4;

    auto conv = [&](float* emb, const float* xs, const float* xd, int rel, int lr) {
        k_aggr<<<AGGR_GRID, 256, 0, stream>>>(emb, xs, irs + rel * NN, icnt + rel * NN,
                                              icsr + (size_t)rel * EE);
        k_cgemm<<<GEMM_GRID, 256, 0, stream>>>(emb, emb, xd, fWs + (size_t)lr * HH * HH,
                                               fWd + (size_t)lr * HH * HH, fB + lr * HH, NN);
    };

    // ================= layer 0 =================
    conv(B0, xA, xB, 0, 0);  // embB1
    conv(B1, xB, xB, 1, 1);  // embB2
    conv(B2, xB, xA, 2, 2);  // embA
    k_attn<<<1024, 256, 0, stream>>>(B0, attnW1, attnb1, attnw2, P1, NN);
    k_attn<<<1024, 256, 0, stream>>>(B1, attnW1, attnb1, attnw2, P2, NN);
    k_alpha<<<1, 256, 0, stream>>>(P1, P2, alp, 1024, invN);
    hipMemsetAsync(csB, 0, 256 * 4, stream);
    k_comb<true><<<512, 256, 0, stream>>>(B0, B1, alp, csB, csB + 128, NN);
    hipMemsetAsync(csA, 0, 256 * 4, stream);
    k_comb<false><<<512, 256, 0, stream>>>(B2, nullptr, nullptr, csA, csA + 128, NN);
    k_bnp<<<1, 128, 0, stream>>>(csA, csA + 128, gamma + 0 * HH, beta + 0 * HH, scA, scA + 128, invN);
    k_bnp<<<1, 128, 0, stream>>>(csB, csB + 128, gamma + 1 * HH, beta + 1 * HH, scB, scB + 128, invN);
    k_bna<<<(int)(NH / 4 / 256), 256, 0, stream>>>(B2, scA, scA + 128);  // xA = B2
    k_bna<<<(int)(NH / 4 / 256), 256, 0, stream>>>(B0, scB, scB + 128);  // xB = B0

    // ================= layer 1 =================
    conv(B1, B2, B0, 0, 3);  // embB1'
    conv(B3, B0, B0, 1, 4);  // embB2'
    k_attn<<<1024, 256, 0, stream>>>(B1, attnW1 + HH * AAA, attnb1 + AAA, attnw2 + AAA, P1, NN);
    k_attn<<<1024, 256, 0, stream>>>(B3, attnW1 + HH * AAA, attnb1 + AAA, attnw2 + AAA, P2, NN);
    k_alpha<<<1, 256, 0, stream>>>(P1, P2, alp, 1024, invN);
    hipMemsetAsync(csB, 0, 256 * 4, stream);
    k_comb<true><<<512, 256, 0, stream>>>(B1, B3, alp, csB, csB + 128, NN);  // xB_new -> B1
    conv(B3, B0, B2, 2, 5);  // embA'
    hipMemsetAsync(csA, 0, 256 * 4, stream);
    k_comb<false><<<512, 256, 0, stream>>>(B3, nullptr, nullptr, csA, csA + 128, NN);
    k_bnp<<<1, 128, 0, stream>>>(csA, csA + 128, gamma + 2 * HH, beta + 2 * HH, scA, scA + 128, invN);
    k_bnp<<<1, 128, 0, stream>>>(csB, csB + 128, gamma + 3 * HH, beta + 3 * HH, scB, scB + 128, invN);
    k_bna<<<(int)(NH / 4 / 256), 256, 0, stream>>>(B3, scA, scA + 128);  // xA_final = B3
    k_bna<<<(int)(NH / 4 / 256), 256, 0, stream>>>(B1, scB, scB + 128);  // xB_final = B1

    // ================= head =================
    k_fc<<<2048, 256, 0, stream>>>(B3, fcW, fcb, out, NN);
    k_fc<<<2048, 256, 0, stream>>>(B1, fcW + HH * CC, fcb + CC, out + (size_t)NN * CC, NN);
}